// Round 1
// baseline (884.864 us; speedup 1.0000x reference)
//
#include <hip/hip_runtime.h>

#define NB 32
#define NC 128
#define NH 128
#define NW 128
#define SH 64
#define SW 64
#define FLAT (NC*SH*SW)   // 524288

__device__ __forceinline__ float2 cmul(float2 a, float2 b) {
    return make_float2(a.x*b.x - a.y*b.y, a.x*b.y + a.y*b.x);
}

// ---------------- K0: init q_in accumulators with bias ----------------
__global__ void k0_init_qin(const float* __restrict__ q_in_b, float* __restrict__ qin) {
    int idx = blockIdx.x*256 + threadIdx.x;
    if (idx < 1024) {
        int k = idx >> 8, q = idx & 7;
        qin[idx] = q_in_b[k*8 + q];
    }
}

// ---------------- K1: q_in[k][b][q] += DWT(x) . W_in -----------------
// grid (128 c-planes, 4 b-groups), block 512 = 8 waves; wave -> one b, lane -> j
__global__ __launch_bounds__(512) void k1_qin(const float* __restrict__ x,
                                              const float* __restrict__ qw,
                                              float* __restrict__ qin) {
    int c    = blockIdx.x;
    int bg   = blockIdx.y;
    int wave = threadIdx.x >> 6;
    int lane = threadIdx.x & 63;
    int b    = bg*8 + wave;
    const float* xb = x  + (size_t)(b*NC + c) * (NH*NW);
    const float* Wc = qw + (size_t)c * (SH*SW);
    float acc[32];
    #pragma unroll
    for (int t = 0; t < 32; t++) acc[t] = 0.f;
    for (int i = 0; i < 64; i++) {
        const float* xr = xb + (2*i)*NW + 2*lane;
        float2 t0 = *(const float2*)xr;          // row 2i   : a,b
        float2 t1 = *(const float2*)(xr + NW);   // row 2i+1 : c,d
        float s0 = (t0.x + t0.y + t1.x + t1.y)*0.5f;  // ll
        float s1 = (t0.x + t0.y - t1.x - t1.y)*0.5f;  // lh
        float s2 = (t0.x - t0.y + t1.x - t1.y)*0.5f;  // hl
        float s3 = (t0.x - t0.y - t1.x + t1.y)*0.5f;  // hh
        int fo = i*64 + lane;
        #pragma unroll
        for (int k = 0; k < 4; k++) {
            float s = (k==0) ? s0 : (k==1) ? s1 : (k==2) ? s2 : s3;
            #pragma unroll
            for (int q = 0; q < 8; q++)
                acc[k*8+q] += s * Wc[(size_t)(k*8+q)*FLAT + fo];
        }
    }
    #pragma unroll
    for (int t = 0; t < 32; t++) {
        float v = acc[t];
        #pragma unroll
        for (int off = 32; off >= 1; off >>= 1) v += __shfl_down(v, off, 64);
        if (lane == 0)
            atomicAdd(&qin[(t>>3)*256 + b*8 + (t&7)], v);
    }
}

// ---------------- K2: 8-qubit state-vector sim, 1 block per (k,b) ----
__global__ __launch_bounds__(256) void k2_qsim(const float* __restrict__ qin,
                                               const float* __restrict__ qweights,
                                               float* __restrict__ ev) {
    int k = blockIdx.x >> 5, b = blockIdx.x & 31;
    int tid = threadIdx.x;
    __shared__ float2 st[256];
    __shared__ float  pr[256];
    __shared__ float  ang[8];
    if (tid < 8) ang[tid] = qin[(k*32+b)*8 + tid];
    st[tid] = make_float2(tid == 0 ? 1.f : 0.f, 0.f);
    __syncthreads();
    // RX(angle_q) on qubit q  (bit position 7-q, axis order MSB-first)
    for (int q = 0; q < 8; q++) {
        int bp = 7-q;
        float h = 0.5f*ang[q];
        float cA = cosf(h), sA = sinf(h);
        float2 self = st[tid];
        float2 part = st[tid ^ (1<<bp)];
        float2 nv = make_float2(cA*self.x + sA*part.y, cA*self.y - sA*part.x);
        __syncthreads(); st[tid] = nv; __syncthreads();
    }
    for (int l = 0; l < 3; l++) {
        for (int q = 0; q < 8; q++) {
            const float* w = qweights + ((k*3 + l)*8 + q)*3;
            float phi = w[0], th = w[1], om = w[2];
            float ct = cosf(0.5f*th), sst = sinf(0.5f*th);
            float ap = -0.5f*(phi+om), am = -0.5f*(phi-om);
            float cp = cosf(ap), sp = sinf(ap), cm = cosf(am), sm = sinf(am);
            float2 U00 = make_float2( cp*ct,  sp*ct);
            float2 U01 = make_float2(-cm*sst, sm*sst);
            float2 U10 = make_float2( cm*sst, sm*sst);
            float2 U11 = make_float2( cp*ct, -sp*ct);
            int bp = 7-q;
            int bit = (tid>>bp)&1;
            float2 self = st[tid], part = st[tid ^ (1<<bp)];
            float2 m0, m1;
            if (bit == 0) { m0 = cmul(U00, self); m1 = cmul(U01, part); }
            else          { m0 = cmul(U10, part); m1 = cmul(U11, self); }
            float2 nv = make_float2(m0.x + m1.x, m0.y + m1.y);
            __syncthreads(); st[tid] = nv; __syncthreads();
        }
        // CNOT chain (q -> q+1), then (7 -> 0)
        for (int q = 0; q < 7; q++) {
            int bc = 7-q, bt = 6-q;
            float2 v = ((tid>>bc)&1) ? st[tid ^ (1<<bt)] : st[tid];
            __syncthreads(); st[tid] = v; __syncthreads();
        }
        {
            int bc = 0, bt = 7;
            float2 v = ((tid>>bc)&1) ? st[tid ^ (1<<bt)] : st[tid];
            __syncthreads(); st[tid] = v; __syncthreads();
        }
    }
    pr[tid] = st[tid].x*st[tid].x + st[tid].y*st[tid].y;
    __syncthreads();
    if (tid < 8) {
        int bp = 7 - tid;
        float s = 0.f;
        for (int i = 0; i < 256; i++) s += ((i>>bp)&1) ? -pr[i] : pr[i];
        ev[(k*32+b)*8 + tid] = s;
    }
}

// ---------------- K3: G = fuse_W @ q_out_W (and Gb = fuse_W @ q_out_b)
// per k: (128o x 128c) @ (128c x 36864n); tile 128x128, micro 8x8
__global__ __launch_bounds__(256) void k3_gemmG(const float* __restrict__ q_out_W,
                                                const float* __restrict__ q_out_b,
                                                const float* __restrict__ fuse_W,
                                                float* __restrict__ Gb,
                                                float* __restrict__ G) {
    int k = blockIdx.x / 288;
    int r = blockIdx.x % 288;
    const float* Bg; float* Og; int ldB; int n0;
    if (r < 256) { n0 = r*128;       Bg = q_out_W + (size_t)k*4194304; ldB = 32768; Og = G  + (size_t)k*4194304; }
    else         { n0 = (r-256)*128; Bg = q_out_b + (size_t)k*FLAT;    ldB = 4096;  Og = Gb + (size_t)k*FLAT; }
    __shared__ float As[32*132];  // As[cc][o]  (A^T, padded)
    __shared__ float Bs[32*132];  // Bs[cc][n]
    int tid = threadIdx.x;
    int ty = tid >> 4, tx = tid & 15;
    float acc[8][8];
    #pragma unroll
    for (int m = 0; m < 8; m++)
        #pragma unroll
        for (int n = 0; n < 8; n++) acc[m][n] = 0.f;
    for (int c0 = 0; c0 < 128; c0 += 32) {
        for (int idx = tid; idx < 32*128; idx += 256) {
            int o = idx >> 5, cc = idx & 31;
            As[cc*132 + o] = fuse_W[o*128 + c0 + cc];
        }
        for (int idx = tid; idx < 32*128; idx += 256) {
            int cc = idx >> 7, n = idx & 127;
            Bs[cc*132 + n] = Bg[(size_t)(c0+cc)*ldB + n0 + n];
        }
        __syncthreads();
        #pragma unroll 2
        for (int cc = 0; cc < 32; cc++) {
            float4 a0 = *(const float4*)&As[cc*132 + ty*8];
            float4 a1 = *(const float4*)&As[cc*132 + ty*8 + 4];
            float4 b0 = *(const float4*)&Bs[cc*132 + tx*8];
            float4 b1 = *(const float4*)&Bs[cc*132 + tx*8 + 4];
            float av[8] = {a0.x,a0.y,a0.z,a0.w,a1.x,a1.y,a1.z,a1.w};
            float bv[8] = {b0.x,b0.y,b0.z,b0.w,b1.x,b1.y,b1.z,b1.w};
            #pragma unroll
            for (int m = 0; m < 8; m++)
                #pragma unroll
                for (int n = 0; n < 8; n++) acc[m][n] += av[m]*bv[n];
        }
        __syncthreads();
    }
    #pragma unroll
    for (int mm = 0; mm < 8; mm++) {
        int m = ty*8 + mm;
        float* orow = Og + (size_t)m*ldB + n0 + tx*8;
        *(float4*)orow       = make_float4(acc[mm][0], acc[mm][1], acc[mm][2], acc[mm][3]);
        *(float4*)(orow + 4) = make_float4(acc[mm][4], acc[mm][5], acc[mm][6], acc[mm][7]);
    }
}

// ---------------- K4: epilogue out = x + fuse_b + IDWT(ev . G + Gb) --
// grid (64 i, 128 o), block 256 = 4 waves; lane -> j, wave -> 8 b's
__global__ __launch_bounds__(256) void k4_epilogue(const float* __restrict__ x,
                                                   const float* __restrict__ ev,
                                                   const float* __restrict__ Gb,
                                                   const float* __restrict__ G,
                                                   const float* __restrict__ fuse_b,
                                                   float* __restrict__ out) {
    int i    = blockIdx.x;          // 0..63
    int o    = blockIdx.y;          // 0..127
    int lane = threadIdx.x & 63;    // j
    int wg   = threadIdx.x >> 6;
    float4 g[4][2]; float gb[4];
    #pragma unroll
    for (int k = 0; k < 4; k++) {
        const float* gp = G + ((size_t)((k*128+o)*4096) + i*64 + lane)*8;
        g[k][0] = *(const float4*)gp;
        g[k][1] = *(const float4*)(gp + 4);
        gb[k]   = Gb[(size_t)(k*128+o)*4096 + i*64 + lane];
    }
    float fb = fuse_b[o];
    for (int bi = 0; bi < 8; bi++) {
        int b = wg*8 + bi;
        float T[4];
        #pragma unroll
        for (int k = 0; k < 4; k++) {
            const float* e = ev + (k*32+b)*8;
            float4 e0 = *(const float4*)e;
            float4 e1 = *(const float4*)(e + 4);
            T[k] = gb[k]
                 + e0.x*g[k][0].x + e0.y*g[k][0].y + e0.z*g[k][0].z + e0.w*g[k][0].w
                 + e1.x*g[k][1].x + e1.y*g[k][1].y + e1.z*g[k][1].z + e1.w*g[k][1].w;
        }
        float pa = 0.5f*(T[0]+T[1]+T[2]+T[3]) + fb;
        float pb = 0.5f*(T[0]+T[1]-T[2]-T[3]) + fb;
        float pc = 0.5f*(T[0]-T[1]+T[2]-T[3]) + fb;
        float pd = 0.5f*(T[0]-T[1]-T[2]+T[3]) + fb;
        size_t base = ((size_t)(b*128 + o)*128 + 2*i)*128 + 2*lane;
        float2 x0 = *(const float2*)(x + base);
        float2 x1 = *(const float2*)(x + base + 128);
        *(float2*)(out + base)       = make_float2(x0.x + pa, x0.y + pb);
        *(float2*)(out + base + 128) = make_float2(x1.x + pc, x1.y + pd);
    }
}

extern "C" void kernel_launch(void* const* d_in, const int* in_sizes, int n_in,
                              void* d_out, int out_size, void* d_ws, size_t ws_size,
                              hipStream_t stream) {
    const float* x         = (const float*)d_in[0];
    const float* q_in_W    = (const float*)d_in[1];
    const float* q_in_b    = (const float*)d_in[2];
    const float* q_weights = (const float*)d_in[3];
    const float* q_out_W   = (const float*)d_in[4];
    const float* q_out_b   = (const float*)d_in[5];
    const float* fuse_W    = (const float*)d_in[6];
    const float* fuse_b    = (const float*)d_in[7];
    float* out = (float*)d_out;

    float* wsf = (float*)d_ws;
    float* qin = wsf;                         // 1024 floats  [k][b][q]
    float* ev  = wsf + 1024;                  // 1024 floats  [k][b][q]
    float* Gb  = wsf + 2048;                  // 4*128*4096   [k][o][p]
    float* G   = wsf + 2048 + 4*128*4096;     // 4*128*4096*8 [k][o][p][q]

    k0_init_qin<<<4, 256, 0, stream>>>(q_in_b, qin);
    k1_qin<<<dim3(128, 4), 512, 0, stream>>>(x, q_in_W, qin);
    k2_qsim<<<128, 256, 0, stream>>>(qin, q_weights, ev);
    k3_gemmG<<<1152, 256, 0, stream>>>(q_out_W, q_out_b, fuse_W, Gb, G);
    k4_epilogue<<<dim3(64, 128), 256, 0, stream>>>(x, ev, Gb, G, fuse_b, out);
}